// Round 1
// baseline (159.149 us; speedup 1.0000x reference)
//
#include <hip/hip_runtime.h>
#include <math.h>

#define U 128

// ---------------------------------------------------------------------------
// K1: Z = X @ Wi^T + bi      X:[B,K=784]  Wi:[128,784]  Z:[B,128]
// grid: B/16 blocks, 256 threads. 16-row tile, k-chunks of 32 staged in LDS.
// ---------------------------------------------------------------------------
__global__ __launch_bounds__(256) void k_input(const float* __restrict__ X,
                                               const float* __restrict__ Wi,
                                               const float* __restrict__ bi,
                                               float* __restrict__ Z,
                                               int B, int K) {
    const int KC = 32;
    __shared__ float xs[16][KC];     // 2 KB
    __shared__ float wt[KC][132];    // 16.9 KB, wt[k][c] = Wi[c][k], padded to 132
    const int tid = threadIdx.x;
    const int r0  = blockIdx.x * 16;
    const int rg  = tid >> 5;        // 0..7  -> rows rg*2 + {0,1}
    const int cg  = tid & 31;        // 0..31 -> cols 4*cg .. +3
    const int c0  = cg * 4;

    float acc0[4] = {0.f, 0.f, 0.f, 0.f};
    float acc1[4] = {0.f, 0.f, 0.f, 0.f};

    for (int kc = 0; kc < K; kc += KC) {
        __syncthreads();
        // stage xs (threads 0..127): 16 rows x 32 k
        if (tid < 128) {
            int r = tid >> 3, f = tid & 7;
            int k = kc + 4 * f;
            float4 v = make_float4(0.f, 0.f, 0.f, 0.f);
            if (k + 3 < K) v = *(const float4*)&X[(long)(r0 + r) * K + k];
            *(float4*)&xs[r][4 * f] = v;
        }
        // stage wt transposed: 128 cols x 32 k in 4 passes of 32 cols
        {
            int f  = tid & 7;
            int cb = tid >> 3;       // 0..31
            #pragma unroll
            for (int p = 0; p < 4; ++p) {
                int c = p * 32 + cb;
                int k = kc + 4 * f;
                float4 v = make_float4(0.f, 0.f, 0.f, 0.f);
                if (k + 3 < K) v = *(const float4*)&Wi[(long)c * K + k];
                wt[4 * f + 0][c] = v.x;
                wt[4 * f + 1][c] = v.y;
                wt[4 * f + 2][c] = v.z;
                wt[4 * f + 3][c] = v.w;
            }
        }
        __syncthreads();

        #pragma unroll
        for (int k = 0; k < KC; k += 4) {
            float4 a0 = *(const float4*)&xs[rg * 2 + 0][k];
            float4 a1 = *(const float4*)&xs[rg * 2 + 1][k];
            float4 w;
            w = *(const float4*)&wt[k + 0][c0];
            acc0[0] += a0.x * w.x; acc0[1] += a0.x * w.y; acc0[2] += a0.x * w.z; acc0[3] += a0.x * w.w;
            acc1[0] += a1.x * w.x; acc1[1] += a1.x * w.y; acc1[2] += a1.x * w.z; acc1[3] += a1.x * w.w;
            w = *(const float4*)&wt[k + 1][c0];
            acc0[0] += a0.y * w.x; acc0[1] += a0.y * w.y; acc0[2] += a0.y * w.z; acc0[3] += a0.y * w.w;
            acc1[0] += a1.y * w.x; acc1[1] += a1.y * w.y; acc1[2] += a1.y * w.z; acc1[3] += a1.y * w.w;
            w = *(const float4*)&wt[k + 2][c0];
            acc0[0] += a0.z * w.x; acc0[1] += a0.z * w.y; acc0[2] += a0.z * w.z; acc0[3] += a0.z * w.w;
            acc1[0] += a1.z * w.x; acc1[1] += a1.z * w.y; acc1[2] += a1.z * w.z; acc1[3] += a1.z * w.w;
            w = *(const float4*)&wt[k + 3][c0];
            acc0[0] += a0.w * w.x; acc0[1] += a0.w * w.y; acc0[2] += a0.w * w.z; acc0[3] += a0.w * w.w;
            acc1[0] += a1.w * w.x; acc1[1] += a1.w * w.y; acc1[2] += a1.w * w.z; acc1[3] += a1.w * w.w;
        }
    }

    float4 bv = *(const float4*)&bi[c0];
    float4 o0, o1;
    o0.x = acc0[0] + bv.x; o0.y = acc0[1] + bv.y; o0.z = acc0[2] + bv.z; o0.w = acc0[3] + bv.w;
    o1.x = acc1[0] + bv.x; o1.y = acc1[1] + bv.y; o1.z = acc1[2] + bv.z; o1.w = acc1[3] + bv.w;
    *(float4*)&Z[(long)(r0 + rg * 2 + 0) * U + c0] = o0;
    *(float4*)&Z[(long)(r0 + rg * 2 + 1) * U + c0] = o1;
}

// ---------------------------------------------------------------------------
// K2: implicit block via Picard fixed-point iteration (row-independent):
//     z <- tanh(z @ W^T + x), z0 = tanh(x); converges (contractive W).
// grid: B/8 blocks, 128 threads. W transposed in LDS (64KB) for the whole loop.
// Early exit when block-max |dz| < 3e-6 (cap 50) -- deterministic.
// ---------------------------------------------------------------------------
__global__ __launch_bounds__(128) void k_fixed(const float* __restrict__ W,
                                               const float* __restrict__ Xin,
                                               float* __restrict__ Zout,
                                               int B) {
    __shared__ float wt[U][U];   // 64 KB, wt[k][c] = W[c][k]
    __shared__ float zs[8][U];   // 4 KB
    __shared__ float red[2];

    const int tid = threadIdx.x;
    const int r0  = blockIdx.x * 8;

    // stage W transposed: one thread per weight row c = tid
    {
        const int c = tid;
        #pragma unroll 8
        for (int j = 0; j < U; j += 4) {
            float4 w = *(const float4*)&W[c * U + j];
            wt[j + 0][c] = w.x;
            wt[j + 1][c] = w.y;
            wt[j + 2][c] = w.z;
            wt[j + 3][c] = w.w;
        }
    }

    const int rg  = tid >> 6;        // 0..1  -> rows rg*4 + rr
    const int cg  = tid & 63;        // 0..63 -> cols 2*cg, 2*cg+1
    const int c0  = cg * 2;
    const int rg4 = rg * 4;

    // x into registers, z0 = tanh(x) into LDS
    float xr[4][2];
    #pragma unroll
    for (int rr = 0; rr < 4; ++rr) {
        float2 xv = *(const float2*)&Xin[(long)(r0 + rg4 + rr) * U + c0];
        xr[rr][0] = xv.x;
        xr[rr][1] = xv.y;
        float2 z0 = make_float2(tanhf(xv.x), tanhf(xv.y));
        *(float2*)&zs[rg4 + rr][c0] = z0;
    }
    __syncthreads();

    for (int it = 0; it < 50; ++it) {
        float acc[4][2] = {{0.f,0.f},{0.f,0.f},{0.f,0.f},{0.f,0.f}};
        #pragma unroll 4
        for (int k = 0; k < U; k += 4) {
            float4 zv0 = *(const float4*)&zs[rg4 + 0][k];
            float4 zv1 = *(const float4*)&zs[rg4 + 1][k];
            float4 zv2 = *(const float4*)&zs[rg4 + 2][k];
            float4 zv3 = *(const float4*)&zs[rg4 + 3][k];
            int kk = k;
            #define PICARD_STEP(ZC)                                             \
            {   float2 wv = *(const float2*)&wt[kk][c0];                        \
                acc[0][0] += zv0.ZC * wv.x; acc[0][1] += zv0.ZC * wv.y;         \
                acc[1][0] += zv1.ZC * wv.x; acc[1][1] += zv1.ZC * wv.y;         \
                acc[2][0] += zv2.ZC * wv.x; acc[2][1] += zv2.ZC * wv.y;         \
                acc[3][0] += zv3.ZC * wv.x; acc[3][1] += zv3.ZC * wv.y;         \
                ++kk; }
            PICARD_STEP(x)
            PICARD_STEP(y)
            PICARD_STEP(z)
            PICARD_STEP(w)
            #undef PICARD_STEP
        }

        float zn[4][2];
        float dmax = 0.f;
        #pragma unroll
        for (int rr = 0; rr < 4; ++rr) {
            #pragma unroll
            for (int cc = 0; cc < 2; ++cc) {
                float v = tanhf(acc[rr][cc] + xr[rr][cc]);
                zn[rr][cc] = v;
                float old = zs[rg4 + rr][c0 + cc];
                dmax = fmaxf(dmax, fabsf(v - old));
            }
        }
        __syncthreads();   // everyone done reading old zs
        #pragma unroll
        for (int rr = 0; rr < 4; ++rr)
            *(float2*)&zs[rg4 + rr][c0] = make_float2(zn[rr][0], zn[rr][1]);

        #pragma unroll
        for (int off = 32; off > 0; off >>= 1)
            dmax = fmaxf(dmax, __shfl_xor(dmax, off));
        if ((tid & 63) == 0) red[tid >> 6] = dmax;
        __syncthreads();   // zs + red visible
        if (fmaxf(red[0], red[1]) < 3e-6f) break;
    }

    // write converged z (8 rows x 128 cols)
    {
        const int r = tid >> 4;          // 0..7
        const int q = (tid & 15) * 8;    // 0..120 step 8
        *(float4*)&Zout[(long)(r0 + r) * U + q + 0] = *(const float4*)&zs[r][q + 0];
        *(float4*)&Zout[(long)(r0 + r) * U + q + 4] = *(const float4*)&zs[r][q + 4];
    }
}

// ---------------------------------------------------------------------------
// K3: Out = softmax(Z @ Wo^T + bo)   Z:[B,128] Wo:[10,128] -> Out:[B,10]
// one wave per row; shuffle-reduce dots; redundant per-lane softmax.
// ---------------------------------------------------------------------------
__global__ __launch_bounds__(256) void k_out(const float* __restrict__ Z,
                                             const float* __restrict__ Wo,
                                             const float* __restrict__ bo,
                                             float* __restrict__ Out,
                                             int B) {
    const int tid  = threadIdx.x;
    const int lane = tid & 63;
    const int row  = blockIdx.x * 4 + (tid >> 6);

    const float z0 = Z[(long)row * U + lane];
    const float z1 = Z[(long)row * U + 64 + lane];

    float e[10];
    float m = -1e30f;
    #pragma unroll
    for (int o = 0; o < 10; ++o) {
        float p = z0 * Wo[o * U + lane] + z1 * Wo[o * U + 64 + lane];
        #pragma unroll
        for (int off = 32; off > 0; off >>= 1)
            p += __shfl_xor(p, off);
        p += bo[o];
        e[o] = p;
        m = fmaxf(m, p);
    }
    float s = 0.f;
    #pragma unroll
    for (int o = 0; o < 10; ++o) {
        e[o] = expf(e[o] - m);
        s += e[o];
    }
    const float inv = 1.0f / s;
    float v = 0.f;
    #pragma unroll
    for (int o = 0; o < 10; ++o)
        if (lane == o) v = e[o] * inv;
    if (lane < 10) Out[(long)row * 10 + lane] = v;
}

// ---------------------------------------------------------------------------
extern "C" void kernel_launch(void* const* d_in, const int* in_sizes, int n_in,
                              void* d_out, int out_size, void* d_ws, size_t ws_size,
                              hipStream_t stream) {
    const float* x  = (const float*)d_in[0];   // [B,784]
    const float* Wi = (const float*)d_in[1];   // [128,784]
    const float* bi = (const float*)d_in[2];   // [128]
    const float* Wb = (const float*)d_in[3];   // [L,128,128]
    const float* Wo = (const float*)d_in[4];   // [10,128]
    const float* bo = (const float*)d_in[5];   // [10]
    float* out = (float*)d_out;

    const int DIN = 784;
    const int B   = in_sizes[0] / DIN;             // 2048
    const int L   = in_sizes[3] / (U * U);         // 2

    float* zA = (float*)d_ws;
    float* zB = zA + (size_t)B * U;

    k_input<<<B / 16, 256, 0, stream>>>(x, Wi, bi, zA, B, DIN);

    float* cur = zA;
    float* nxt = zB;
    for (int l = 0; l < L; ++l) {
        k_fixed<<<B / 8, 128, 0, stream>>>(Wb + (size_t)l * U * U, cur, nxt, B);
        float* t = cur; cur = nxt; nxt = t;
    }

    k_out<<<B / 4, 256, 0, stream>>>(cur, Wo, bo, out, B);
}

// Round 2
// 82.486 us; speedup vs baseline: 1.9294x; 1.9294x over previous
//
#include <hip/hip_runtime.h>
#include <math.h>

#define U 128

typedef __attribute__((ext_vector_type(8))) short bf16x8;
typedef __attribute__((ext_vector_type(4))) float f32x4;
typedef __attribute__((ext_vector_type(4))) unsigned int u32x4;

__device__ inline unsigned int pack2(float a, float b) {
    // low short = bf16(a) (truncated), high short = bf16(b)
    return (__float_as_uint(a) >> 16) | (__float_as_uint(b) & 0xFFFF0000u);
}
__device__ inline float lo_of(float a) {
    return a - __uint_as_float(__float_as_uint(a) & 0xFFFF0000u);
}
__device__ inline float tanh_fast(float v) {
    float e = __expf(2.0f * v);
    return 1.0f - 2.0f / (e + 1.0f);
}

// ---------------------------------------------------------------------------
// k_prep: split W (f32) into truncated-bf16 hi + bf16 lo arrays.
// ---------------------------------------------------------------------------
__global__ __launch_bounds__(256) void k_prep(const float* __restrict__ W,
                                              unsigned short* __restrict__ Wh,
                                              unsigned short* __restrict__ Wl,
                                              int total4) {
    int i = blockIdx.x * blockDim.x + threadIdx.x;
    if (i >= total4) return;
    float4 v = *(const float4*)&W[i * 4];
    uint2 hh, ll;
    hh.x = pack2(v.x, v.y);
    hh.y = pack2(v.z, v.w);
    ll.x = pack2(lo_of(v.x), lo_of(v.y));
    ll.y = pack2(lo_of(v.z), lo_of(v.w));
    *(uint2*)&Wh[i * 4] = hh;
    *(uint2*)&Wl[i * 4] = ll;
}

// ---------------------------------------------------------------------------
// K1: Z = X @ Wi^T + bi      X:[B,K=784]  Wi:[128,784]  Z:[B,128]  (unchanged)
// ---------------------------------------------------------------------------
__global__ __launch_bounds__(256) void k_input(const float* __restrict__ X,
                                               const float* __restrict__ Wi,
                                               const float* __restrict__ bi,
                                               float* __restrict__ Z,
                                               int B, int K) {
    const int KC = 32;
    __shared__ float xs[16][KC];
    __shared__ float wt[KC][132];
    const int tid = threadIdx.x;
    const int r0  = blockIdx.x * 16;
    const int rg  = tid >> 5;
    const int cg  = tid & 31;
    const int c0  = cg * 4;

    float acc0[4] = {0.f, 0.f, 0.f, 0.f};
    float acc1[4] = {0.f, 0.f, 0.f, 0.f};

    for (int kc = 0; kc < K; kc += KC) {
        __syncthreads();
        if (tid < 128) {
            int r = tid >> 3, f = tid & 7;
            int k = kc + 4 * f;
            float4 v = make_float4(0.f, 0.f, 0.f, 0.f);
            if (k + 3 < K) v = *(const float4*)&X[(long)(r0 + r) * K + k];
            *(float4*)&xs[r][4 * f] = v;
        }
        {
            int f  = tid & 7;
            int cb = tid >> 3;
            #pragma unroll
            for (int p = 0; p < 4; ++p) {
                int c = p * 32 + cb;
                int k = kc + 4 * f;
                float4 v = make_float4(0.f, 0.f, 0.f, 0.f);
                if (k + 3 < K) v = *(const float4*)&Wi[(long)c * K + k];
                wt[4 * f + 0][c] = v.x;
                wt[4 * f + 1][c] = v.y;
                wt[4 * f + 2][c] = v.z;
                wt[4 * f + 3][c] = v.w;
            }
        }
        __syncthreads();

        #pragma unroll
        for (int k = 0; k < KC; k += 4) {
            float4 a0 = *(const float4*)&xs[rg * 2 + 0][k];
            float4 a1 = *(const float4*)&xs[rg * 2 + 1][k];
            float4 w;
            w = *(const float4*)&wt[k + 0][c0];
            acc0[0] += a0.x * w.x; acc0[1] += a0.x * w.y; acc0[2] += a0.x * w.z; acc0[3] += a0.x * w.w;
            acc1[0] += a1.x * w.x; acc1[1] += a1.x * w.y; acc1[2] += a1.x * w.z; acc1[3] += a1.x * w.w;
            w = *(const float4*)&wt[k + 1][c0];
            acc0[0] += a0.y * w.x; acc0[1] += a0.y * w.y; acc0[2] += a0.y * w.z; acc0[3] += a0.y * w.w;
            acc1[0] += a1.y * w.x; acc1[1] += a1.y * w.y; acc1[2] += a1.y * w.z; acc1[3] += a1.y * w.w;
            w = *(const float4*)&wt[k + 2][c0];
            acc0[0] += a0.z * w.x; acc0[1] += a0.z * w.y; acc0[2] += a0.z * w.z; acc0[3] += a0.z * w.w;
            acc1[0] += a1.z * w.x; acc1[1] += a1.z * w.y; acc1[2] += a1.z * w.z; acc1[3] += a1.z * w.w;
            w = *(const float4*)&wt[k + 3][c0];
            acc0[0] += a0.w * w.x; acc0[1] += a0.w * w.y; acc0[2] += a0.w * w.z; acc0[3] += a0.w * w.w;
            acc1[0] += a1.w * w.x; acc1[1] += a1.w * w.y; acc1[2] += a1.w * w.z; acc1[3] += a1.w * w.w;
        }
    }

    float4 bv = *(const float4*)&bi[c0];
    float4 o0, o1;
    o0.x = acc0[0] + bv.x; o0.y = acc0[1] + bv.y; o0.z = acc0[2] + bv.z; o0.w = acc0[3] + bv.w;
    o1.x = acc1[0] + bv.x; o1.y = acc1[1] + bv.y; o1.z = acc1[2] + bv.z; o1.w = acc1[3] + bv.w;
    *(float4*)&Z[(long)(r0 + rg * 2 + 0) * U + c0] = o0;
    *(float4*)&Z[(long)(r0 + rg * 2 + 1) * U + c0] = o1;
}

// ---------------------------------------------------------------------------
// k_fixed2: Picard fixed point z <- tanh(z @ W^T + x) via MFMA, 3-term bf16
// split (~f32 accuracy). Block = 16 rows, 4 waves; wave = 32 cols; W-frags in
// VGPRs for the whole loop; z round-trips through double-buffered LDS.
//
// MFMA 16x16x32_bf16 layouts (verified m89/m91):
//   A: row = lane&15, k = (lane>>4)*8 + e       (z)
//   B: col = lane&15, k = (lane>>4)*8 + e       (B[k][c] = W[c][k])
//   C/D: col = lane&15, row = (lane>>4)*4 + reg
// ---------------------------------------------------------------------------
__global__ __launch_bounds__(256, 1) void k_fixed2(const unsigned short* __restrict__ Wh,
                                                   const unsigned short* __restrict__ Wl,
                                                   const float* __restrict__ Xin,
                                                   float* __restrict__ Zout) {
    __shared__ float zf[2][16][132];
    __shared__ float red[2][4];

    const int tid  = threadIdx.x;
    const int w    = tid >> 6;
    const int lane = tid & 63;
    const int r0   = blockIdx.x * 16;
    const int l15  = lane & 15;
    const int lq   = lane >> 4;          // 0..3
    const int cb   = w * 32;             // wave col base

    // W fragments: constant across iterations -> registers (64 VGPR/wave)
    bf16x8 whf[2][4], wlf[2][4];
    #pragma unroll
    for (int ct = 0; ct < 2; ++ct) {
        const int c = cb + 16 * ct + l15;
        #pragma unroll
        for (int ks = 0; ks < 4; ++ks) {
            const int k = ks * 32 + lq * 8;
            whf[ct][ks] = *(const bf16x8*)&Wh[c * U + k];
            wlf[ct][ks] = *(const bf16x8*)&Wl[c * U + k];
        }
    }

    // x fragments in C/D layout; z0 = tanh(x)
    float xf[2][4], zr[2][4];
    #pragma unroll
    for (int ct = 0; ct < 2; ++ct) {
        const int c = cb + 16 * ct + l15;
        #pragma unroll
        for (int i = 0; i < 4; ++i) {
            const int r = r0 + lq * 4 + i;
            float xv = Xin[(long)r * U + c];
            xf[ct][i] = xv;
            float z0 = tanh_fast(xv);
            zr[ct][i] = z0;
            zf[0][lq * 4 + i][c] = z0;
        }
    }
    __syncthreads();

    int cur = 0;
    for (int it = 0; it < 50; ++it) {
        // read A fragments (z) from LDS, split into bf16 hi/lo
        bf16x8 zh[4], zl[4];
        #pragma unroll
        for (int ks = 0; ks < 4; ++ks) {
            const float* zp = &zf[cur][l15][ks * 32 + lq * 8];
            float4 p = *(const float4*)zp;
            float4 q = *(const float4*)(zp + 4);
            u32x4 h, lo;
            h[0] = pack2(p.x, p.y); h[1] = pack2(p.z, p.w);
            h[2] = pack2(q.x, q.y); h[3] = pack2(q.z, q.w);
            lo[0] = pack2(lo_of(p.x), lo_of(p.y));
            lo[1] = pack2(lo_of(p.z), lo_of(p.w));
            lo[2] = pack2(lo_of(q.x), lo_of(q.y));
            lo[3] = pack2(lo_of(q.z), lo_of(q.w));
            zh[ks] = __builtin_bit_cast(bf16x8, h);
            zl[ks] = __builtin_bit_cast(bf16x8, lo);
        }

        float dmax = 0.0f;
        float znew[2][4];
        #pragma unroll
        for (int ct = 0; ct < 2; ++ct) {
            f32x4 a0 = {xf[ct][0], xf[ct][1], xf[ct][2], xf[ct][3]};  // C-init = x
            f32x4 a1 = {0.f, 0.f, 0.f, 0.f};
            f32x4 a2 = {0.f, 0.f, 0.f, 0.f};
            #pragma unroll
            for (int ks = 0; ks < 4; ++ks) {
                a0 = __builtin_amdgcn_mfma_f32_16x16x32_bf16(zh[ks], whf[ct][ks], a0, 0, 0, 0);
                a1 = __builtin_amdgcn_mfma_f32_16x16x32_bf16(zl[ks], whf[ct][ks], a1, 0, 0, 0);
                a2 = __builtin_amdgcn_mfma_f32_16x16x32_bf16(zh[ks], wlf[ct][ks], a2, 0, 0, 0);
            }
            #pragma unroll
            for (int i = 0; i < 4; ++i) {
                float zlin = a0[i] + a1[i] + a2[i];
                float t = tanh_fast(zlin);
                znew[ct][i] = t;
                dmax = fmaxf(dmax, fabsf(t - zr[ct][i]));
                zr[ct][i] = t;
            }
        }

        const int nxt = cur ^ 1;
        #pragma unroll
        for (int ct = 0; ct < 2; ++ct) {
            const int c = cb + 16 * ct + l15;
            #pragma unroll
            for (int i = 0; i < 4; ++i)
                zf[nxt][lq * 4 + i][c] = znew[ct][i];
        }

        #pragma unroll
        for (int off = 32; off > 0; off >>= 1)
            dmax = fmaxf(dmax, __shfl_xor(dmax, off));
        if (lane == 0) red[it & 1][w] = dmax;
        __syncthreads();               // one barrier per iteration
        cur = nxt;
        float g = fmaxf(fmaxf(red[it & 1][0], red[it & 1][1]),
                        fmaxf(red[it & 1][2], red[it & 1][3]));
        if (g < 1e-5f) break;
    }

    // converged z lives in zr registers
    #pragma unroll
    for (int ct = 0; ct < 2; ++ct) {
        const int c = cb + 16 * ct + l15;
        #pragma unroll
        for (int i = 0; i < 4; ++i)
            Zout[(long)(r0 + lq * 4 + i) * U + c] = zr[ct][i];
    }
}

// ---------------------------------------------------------------------------
// K3: Out = softmax(Z @ Wo^T + bo)   (unchanged)
// ---------------------------------------------------------------------------
__global__ __launch_bounds__(256) void k_out(const float* __restrict__ Z,
                                             const float* __restrict__ Wo,
                                             const float* __restrict__ bo,
                                             float* __restrict__ Out,
                                             int B) {
    const int tid  = threadIdx.x;
    const int lane = tid & 63;
    const int row  = blockIdx.x * 4 + (tid >> 6);

    const float z0 = Z[(long)row * U + lane];
    const float z1 = Z[(long)row * U + 64 + lane];

    float e[10];
    float m = -1e30f;
    #pragma unroll
    for (int o = 0; o < 10; ++o) {
        float p = z0 * Wo[o * U + lane] + z1 * Wo[o * U + 64 + lane];
        #pragma unroll
        for (int off = 32; off > 0; off >>= 1)
            p += __shfl_xor(p, off);
        p += bo[o];
        e[o] = p;
        m = fmaxf(m, p);
    }
    float s = 0.f;
    #pragma unroll
    for (int o = 0; o < 10; ++o) {
        e[o] = expf(e[o] - m);
        s += e[o];
    }
    const float inv = 1.0f / s;
    float v = 0.f;
    #pragma unroll
    for (int o = 0; o < 10; ++o)
        if (lane == o) v = e[o] * inv;
    if (lane < 10) Out[(long)row * 10 + lane] = v;
}

// ---------------------------------------------------------------------------
extern "C" void kernel_launch(void* const* d_in, const int* in_sizes, int n_in,
                              void* d_out, int out_size, void* d_ws, size_t ws_size,
                              hipStream_t stream) {
    const float* x  = (const float*)d_in[0];   // [B,784]
    const float* Wi = (const float*)d_in[1];   // [128,784]
    const float* bi = (const float*)d_in[2];   // [128]
    const float* Wb = (const float*)d_in[3];   // [L,128,128]
    const float* Wo = (const float*)d_in[4];   // [10,128]
    const float* bo = (const float*)d_in[5];   // [10]
    float* out = (float*)d_out;

    const int DIN = 784;
    const int B   = in_sizes[0] / DIN;             // 2048
    const int L   = in_sizes[3] / (U * U);         // 2

    float* zA = (float*)d_ws;
    float* zB = zA + (size_t)B * U;
    unsigned short* WhAll = (unsigned short*)(zB + (size_t)B * U);
    unsigned short* WlAll = WhAll + (size_t)L * U * U;

    const int total4 = L * U * U / 4;
    k_prep<<<(total4 + 255) / 256, 256, 0, stream>>>(Wb, WhAll, WlAll, total4);

    k_input<<<B / 16, 256, 0, stream>>>(x, Wi, bi, zA, B, DIN);

    float* cur = zA;
    float* nxt = zB;
    for (int l = 0; l < L; ++l) {
        k_fixed2<<<B / 16, 256, 0, stream>>>(WhAll + (size_t)l * U * U,
                                             WlAll + (size_t)l * U * U, cur, nxt);
        float* t = cur; cur = nxt; nxt = t;
    }

    k_out<<<B / 4, 256, 0, stream>>>(cur, Wo, bo, out, B);
}

// Round 3
// 62.246 us; speedup vs baseline: 2.5568x; 1.3252x over previous
//
#include <hip/hip_runtime.h>
#include <math.h>

#define U 128

typedef __attribute__((ext_vector_type(8))) short bf16x8;
typedef __attribute__((ext_vector_type(4))) float f32x4;
typedef __attribute__((ext_vector_type(4))) unsigned int u32x4;

__device__ inline unsigned int pack2(float a, float b) {
    // low short = bf16(a) (truncated), high short = bf16(b)
    return (__float_as_uint(a) >> 16) | (__float_as_uint(b) & 0xFFFF0000u);
}
__device__ inline float lo_of(float a) {
    return a - __uint_as_float(__float_as_uint(a) & 0xFFFF0000u);
}
__device__ inline float tanh_fast(float v) {
    float e = __expf(2.0f * v);
    return 1.0f - 2.0f / (e + 1.0f);
}

// ---------------------------------------------------------------------------
// k_prep: split W (f32) into truncated-bf16 hi + bf16 lo arrays (for k_fixed2).
// ---------------------------------------------------------------------------
__global__ __launch_bounds__(256) void k_prep(const float* __restrict__ W,
                                              unsigned short* __restrict__ Wh,
                                              unsigned short* __restrict__ Wl,
                                              int total4) {
    int i = blockIdx.x * blockDim.x + threadIdx.x;
    if (i >= total4) return;
    float4 v = *(const float4*)&W[i * 4];
    uint2 hh, ll;
    hh.x = pack2(v.x, v.y);
    hh.y = pack2(v.z, v.w);
    ll.x = pack2(lo_of(v.x), lo_of(v.y));
    ll.y = pack2(lo_of(v.z), lo_of(v.w));
    *(uint2*)&Wh[i * 4] = hh;
    *(uint2*)&Wl[i * 4] = ll;
}

// ---------------------------------------------------------------------------
// k_input2: Z = X @ Wi^T + bi via MFMA, 3-term bf16 split, no LDS/barriers.
// X:[B,784] Wi:[128,784] Z:[B,128]
// grid = (B/16) * 2 col-halves, 256 thr; wave w owns 16 rows x 16 cols.
// A-frag: row=lane&15, k=(lane>>4)*8+e  (contiguous k in X row)
// B-frag: col=lane&15, k=(lane>>4)*8+e  (contiguous k in Wi row)
// C/D:    col=lane&15, row=(lane>>4)*4+i
// K=784 = 24*32 + 16 (tail chunk valid only for lq<2).
// ---------------------------------------------------------------------------
__global__ __launch_bounds__(256) void k_input2(const float* __restrict__ X,
                                                const float* __restrict__ Wi,
                                                const float* __restrict__ bi,
                                                float* __restrict__ Z) {
    const int KD   = 784;
    const int tid  = threadIdx.x;
    const int w    = tid >> 6;
    const int lane = tid & 63;
    const int l15  = lane & 15;
    const int lq   = lane >> 4;
    const int r0   = (blockIdx.x >> 1) * 16;
    const int c0   = (blockIdx.x & 1) * 64 + w * 16;
    const int row  = r0 + l15;
    const int col  = c0 + l15;

    const float bv = bi[col];
    f32x4 a0 = {bv, bv, bv, bv};
    f32x4 a1 = {0.f, 0.f, 0.f, 0.f};
    f32x4 a2 = {0.f, 0.f, 0.f, 0.f};

    const float* xp = &X[(long)row * KD];
    const float* wp = &Wi[(long)col * KD];

    #define SPLIT8(P4, Q4, H, LO)                                              \
    {   u32x4 h_, l_;                                                          \
        h_[0] = pack2(P4.x, P4.y); h_[1] = pack2(P4.z, P4.w);                  \
        h_[2] = pack2(Q4.x, Q4.y); h_[3] = pack2(Q4.z, Q4.w);                  \
        l_[0] = pack2(lo_of(P4.x), lo_of(P4.y));                               \
        l_[1] = pack2(lo_of(P4.z), lo_of(P4.w));                               \
        l_[2] = pack2(lo_of(Q4.x), lo_of(Q4.y));                               \
        l_[3] = pack2(lo_of(Q4.z), lo_of(Q4.w));                               \
        H  = __builtin_bit_cast(bf16x8, h_);                                   \
        LO = __builtin_bit_cast(bf16x8, l_); }

    #pragma unroll 4
    for (int kc = 0; kc < 24; ++kc) {
        const int k = kc * 32 + lq * 8;
        float4 xa = *(const float4*)&xp[k];
        float4 xb = *(const float4*)&xp[k + 4];
        float4 wa = *(const float4*)&wp[k];
        float4 wb = *(const float4*)&wp[k + 4];
        bf16x8 ah, al, bh, bl;
        SPLIT8(xa, xb, ah, al)
        SPLIT8(wa, wb, bh, bl)
        a0 = __builtin_amdgcn_mfma_f32_16x16x32_bf16(ah, bh, a0, 0, 0, 0);
        a1 = __builtin_amdgcn_mfma_f32_16x16x32_bf16(al, bh, a1, 0, 0, 0);
        a2 = __builtin_amdgcn_mfma_f32_16x16x32_bf16(ah, bl, a2, 0, 0, 0);
    }
    // tail: k = 768 + lq*8, valid only lq<2 (768..783)
    {
        const int k = 768 + lq * 8;
        float4 xa = make_float4(0.f,0.f,0.f,0.f), xb = xa, wa = xa, wb = xa;
        if (lq < 2) {
            xa = *(const float4*)&xp[k];
            xb = *(const float4*)&xp[k + 4];
            wa = *(const float4*)&wp[k];
            wb = *(const float4*)&wp[k + 4];
        }
        bf16x8 ah, al, bh, bl;
        SPLIT8(xa, xb, ah, al)
        SPLIT8(wa, wb, bh, bl)
        a0 = __builtin_amdgcn_mfma_f32_16x16x32_bf16(ah, bh, a0, 0, 0, 0);
        a1 = __builtin_amdgcn_mfma_f32_16x16x32_bf16(al, bh, a1, 0, 0, 0);
        a2 = __builtin_amdgcn_mfma_f32_16x16x32_bf16(ah, bl, a2, 0, 0, 0);
    }
    #undef SPLIT8

    #pragma unroll
    for (int i = 0; i < 4; ++i)
        Z[(long)(r0 + lq * 4 + i) * U + col] = a0[i] + a1[i] + a2[i];
}

// ---------------------------------------------------------------------------
// k_fixed2: Picard fixed point z <- tanh(z @ W^T + x) via MFMA, 3-term bf16
// split (~f32 accuracy). Block = 16 rows, 4 waves; wave = 32 cols; W-frags in
// VGPRs for the whole loop; z round-trips through double-buffered LDS.
// ---------------------------------------------------------------------------
__global__ __launch_bounds__(256, 1) void k_fixed2(const unsigned short* __restrict__ Wh,
                                                   const unsigned short* __restrict__ Wl,
                                                   const float* __restrict__ Xin,
                                                   float* __restrict__ Zout) {
    __shared__ float zf[2][16][132];
    __shared__ float red[2][4];

    const int tid  = threadIdx.x;
    const int w    = tid >> 6;
    const int lane = tid & 63;
    const int r0   = blockIdx.x * 16;
    const int l15  = lane & 15;
    const int lq   = lane >> 4;          // 0..3
    const int cb   = w * 32;             // wave col base

    // W fragments: constant across iterations -> registers (64 VGPR/wave)
    bf16x8 whf[2][4], wlf[2][4];
    #pragma unroll
    for (int ct = 0; ct < 2; ++ct) {
        const int c = cb + 16 * ct + l15;
        #pragma unroll
        for (int ks = 0; ks < 4; ++ks) {
            const int k = ks * 32 + lq * 8;
            whf[ct][ks] = *(const bf16x8*)&Wh[c * U + k];
            wlf[ct][ks] = *(const bf16x8*)&Wl[c * U + k];
        }
    }

    // x fragments in C/D layout; z0 = tanh(x)
    float xf[2][4], zr[2][4];
    #pragma unroll
    for (int ct = 0; ct < 2; ++ct) {
        const int c = cb + 16 * ct + l15;
        #pragma unroll
        for (int i = 0; i < 4; ++i) {
            const int r = r0 + lq * 4 + i;
            float xv = Xin[(long)r * U + c];
            xf[ct][i] = xv;
            float z0 = tanh_fast(xv);
            zr[ct][i] = z0;
            zf[0][lq * 4 + i][c] = z0;
        }
    }
    __syncthreads();

    int cur = 0;
    for (int it = 0; it < 50; ++it) {
        // read A fragments (z) from LDS, split into bf16 hi/lo
        bf16x8 zh[4], zl[4];
        #pragma unroll
        for (int ks = 0; ks < 4; ++ks) {
            const float* zp = &zf[cur][l15][ks * 32 + lq * 8];
            float4 p = *(const float4*)zp;
            float4 q = *(const float4*)(zp + 4);
            u32x4 h, lo;
            h[0] = pack2(p.x, p.y); h[1] = pack2(p.z, p.w);
            h[2] = pack2(q.x, q.y); h[3] = pack2(q.z, q.w);
            lo[0] = pack2(lo_of(p.x), lo_of(p.y));
            lo[1] = pack2(lo_of(p.z), lo_of(p.w));
            lo[2] = pack2(lo_of(q.x), lo_of(q.y));
            lo[3] = pack2(lo_of(q.z), lo_of(q.w));
            zh[ks] = __builtin_bit_cast(bf16x8, h);
            zl[ks] = __builtin_bit_cast(bf16x8, lo);
        }

        float dmax = 0.0f;
        float znew[2][4];
        #pragma unroll
        for (int ct = 0; ct < 2; ++ct) {
            f32x4 a0 = {xf[ct][0], xf[ct][1], xf[ct][2], xf[ct][3]};  // C-init = x
            f32x4 a1 = {0.f, 0.f, 0.f, 0.f};
            f32x4 a2 = {0.f, 0.f, 0.f, 0.f};
            #pragma unroll
            for (int ks = 0; ks < 4; ++ks) {
                a0 = __builtin_amdgcn_mfma_f32_16x16x32_bf16(zh[ks], whf[ct][ks], a0, 0, 0, 0);
                a1 = __builtin_amdgcn_mfma_f32_16x16x32_bf16(zl[ks], whf[ct][ks], a1, 0, 0, 0);
                a2 = __builtin_amdgcn_mfma_f32_16x16x32_bf16(zh[ks], wlf[ct][ks], a2, 0, 0, 0);
            }
            #pragma unroll
            for (int i = 0; i < 4; ++i) {
                float zlin = a0[i] + a1[i] + a2[i];
                float t = tanh_fast(zlin);
                znew[ct][i] = t;
                dmax = fmaxf(dmax, fabsf(t - zr[ct][i]));
                zr[ct][i] = t;
            }
        }

        const int nxt = cur ^ 1;
        #pragma unroll
        for (int ct = 0; ct < 2; ++ct) {
            const int c = cb + 16 * ct + l15;
            #pragma unroll
            for (int i = 0; i < 4; ++i)
                zf[nxt][lq * 4 + i][c] = znew[ct][i];
        }

        #pragma unroll
        for (int off = 32; off > 0; off >>= 1)
            dmax = fmaxf(dmax, __shfl_xor(dmax, off));
        if (lane == 0) red[it & 1][w] = dmax;
        __syncthreads();               // one barrier per iteration
        cur = nxt;
        float g = fmaxf(fmaxf(red[it & 1][0], red[it & 1][1]),
                        fmaxf(red[it & 1][2], red[it & 1][3]));
        if (g < 1e-5f) break;
    }

    // converged z lives in zr registers
    #pragma unroll
    for (int ct = 0; ct < 2; ++ct) {
        const int c = cb + 16 * ct + l15;
        #pragma unroll
        for (int i = 0; i < 4; ++i)
            Zout[(long)(r0 + lq * 4 + i) * U + c] = zr[ct][i];
    }
}

// ---------------------------------------------------------------------------
// K3: Out = softmax(Z @ Wo^T + bo)
// ---------------------------------------------------------------------------
__global__ __launch_bounds__(256) void k_out(const float* __restrict__ Z,
                                             const float* __restrict__ Wo,
                                             const float* __restrict__ bo,
                                             float* __restrict__ Out,
                                             int B) {
    const int tid  = threadIdx.x;
    const int lane = tid & 63;
    const int row  = blockIdx.x * 4 + (tid >> 6);

    const float z0 = Z[(long)row * U + lane];
    const float z1 = Z[(long)row * U + 64 + lane];

    float e[10];
    float m = -1e30f;
    #pragma unroll
    for (int o = 0; o < 10; ++o) {
        float p = z0 * Wo[o * U + lane] + z1 * Wo[o * U + 64 + lane];
        #pragma unroll
        for (int off = 32; off > 0; off >>= 1)
            p += __shfl_xor(p, off);
        p += bo[o];
        e[o] = p;
        m = fmaxf(m, p);
    }
    float s = 0.f;
    #pragma unroll
    for (int o = 0; o < 10; ++o) {
        e[o] = expf(e[o] - m);
        s += e[o];
    }
    const float inv = 1.0f / s;
    float v = 0.f;
    #pragma unroll
    for (int o = 0; o < 10; ++o)
        if (lane == o) v = e[o] * inv;
    if (lane < 10) Out[(long)row * 10 + lane] = v;
}

// ---------------------------------------------------------------------------
extern "C" void kernel_launch(void* const* d_in, const int* in_sizes, int n_in,
                              void* d_out, int out_size, void* d_ws, size_t ws_size,
                              hipStream_t stream) {
    const float* x  = (const float*)d_in[0];   // [B,784]
    const float* Wi = (const float*)d_in[1];   // [128,784]
    const float* bi = (const float*)d_in[2];   // [128]
    const float* Wb = (const float*)d_in[3];   // [L,128,128]
    const float* Wo = (const float*)d_in[4];   // [10,128]
    const float* bo = (const float*)d_in[5];   // [10]
    float* out = (float*)d_out;

    const int DIN = 784;
    const int B   = in_sizes[0] / DIN;             // 2048
    const int L   = in_sizes[3] / (U * U);         // 2

    float* zA = (float*)d_ws;
    float* zB = zA + (size_t)B * U;
    unsigned short* WhAll = (unsigned short*)(zB + (size_t)B * U);
    unsigned short* WlAll = WhAll + (size_t)L * U * U;

    const int total4 = L * U * U / 4;
    k_prep<<<(total4 + 255) / 256, 256, 0, stream>>>(Wb, WhAll, WlAll, total4);

    k_input2<<<(B / 16) * 2, 256, 0, stream>>>(x, Wi, bi, zA);

    float* cur = zA;
    float* nxt = zB;
    for (int l = 0; l < L; ++l) {
        k_fixed2<<<B / 16, 256, 0, stream>>>(WhAll + (size_t)l * U * U,
                                             WlAll + (size_t)l * U * U, cur, nxt);
        float* t = cur; cur = nxt; nxt = t;
    }

    k_out<<<B / 4, 256, 0, stream>>>(cur, Wo, bo, out, B);
}

// Round 4
// 55.251 us; speedup vs baseline: 2.8805x; 1.1266x over previous
//
#include <hip/hip_runtime.h>
#include <math.h>

#define U 128

typedef __attribute__((ext_vector_type(8))) short bf16x8;
typedef __attribute__((ext_vector_type(4))) float f32x4;

__device__ inline unsigned int pack2(float a, float b) {
    // low short = bf16(a) (truncated), high short = bf16(b)
    return (__float_as_uint(a) >> 16) | (__float_as_uint(b) & 0xFFFF0000u);
}
__device__ inline float lo_of(float a) {
    return a - __uint_as_float(__float_as_uint(a) & 0xFFFF0000u);
}
__device__ inline unsigned short hi16(float a) {
    return (unsigned short)(__float_as_uint(a) >> 16);
}
__device__ inline float fromhi(unsigned short h) {
    return __uint_as_float(((unsigned int)h) << 16);
}
__device__ inline float tanh_fast(float v) {
    float e = __expf(2.0f * v);
    return 1.0f - 2.0f / (e + 1.0f);
}
#define MFMA(A, B, C) __builtin_amdgcn_mfma_f32_16x16x32_bf16(A, B, C, 0, 0, 0)

// ---------------------------------------------------------------------------
// k_split: elementwise f32 -> (trunc-bf16 hi, bf16 lo) for X, Wi, Wb.
// ---------------------------------------------------------------------------
__global__ __launch_bounds__(256) void k_split(
        const float* __restrict__ X, const float* __restrict__ Wi,
        const float* __restrict__ Wb,
        unsigned short* __restrict__ Xh, unsigned short* __restrict__ Xl,
        unsigned short* __restrict__ Wih, unsigned short* __restrict__ Wil,
        unsigned short* __restrict__ Wbh, unsigned short* __restrict__ Wbl,
        int n4X, int n4Wi, int n4Wb) {
    int i = blockIdx.x * blockDim.x + threadIdx.x;
    const float* src;
    unsigned short *dh, *dl;
    int j;
    if (i < n4X)                    { j = i;               src = X;  dh = Xh;  dl = Xl;  }
    else if (i < n4X + n4Wi)        { j = i - n4X;         src = Wi; dh = Wih; dl = Wil; }
    else if (i < n4X + n4Wi + n4Wb) { j = i - n4X - n4Wi;  src = Wb; dh = Wbh; dl = Wbl; }
    else return;
    float4 v = *(const float4*)&src[(long)j * 4];
    uint2 hh, ll;
    hh.x = pack2(v.x, v.y);               hh.y = pack2(v.z, v.w);
    ll.x = pack2(lo_of(v.x), lo_of(v.y)); ll.y = pack2(lo_of(v.z), lo_of(v.w));
    *(uint2*)&dh[(long)j * 4] = hh;
    *(uint2*)&dl[(long)j * 4] = ll;
}

// ---------------------------------------------------------------------------
// k_all: fully fused network. grid = B/16 blocks, 512 threads (8 waves,
// 2 waves/SIMD). Block owns 16 batch rows; wave w owns output cols w*16..+15.
//
// Phase 1: x = X @ Wi^T + bi, 3-term bf16-split MFMA from pre-split globals.
// Phase 2: per layer, Picard z <- tanh(z @ W^T + x). z lives in LDS as
//          PRE-SPLIT bf16 hi/lo (producer splits 4 values; consumer
//          ds_read_b128 -> MFMA directly). XOR swizzle (row&7)<<4 on the
//          within-row byte offset kills the D=128 bank-conflict pathology.
// Phase 3: out = softmax(z @ Wo^T + bo), wave-per-2-rows shuffle reduce.
//
// MFMA 16x16x32_bf16 layouts (verified, carried from R1/R2 kernels):
//   A: row=lane&15, k=(lane>>4)*8+e   B: col=lane&15, k=(lane>>4)*8+e
//   C/D: col=lane&15, row=(lane>>4)*4+i
// ---------------------------------------------------------------------------
__global__ __launch_bounds__(512) void k_all(
        const unsigned short* __restrict__ Xh, const unsigned short* __restrict__ Xl,
        const unsigned short* __restrict__ Wih, const unsigned short* __restrict__ Wil,
        const unsigned short* __restrict__ Wbh, const unsigned short* __restrict__ Wbl,
        const float* __restrict__ bi,
        const float* __restrict__ Wo, const float* __restrict__ bo,
        float* __restrict__ Out, int L) {
    __shared__ unsigned short zh[2][16 * U];   // 8 KB  (hi, double-buffered)
    __shared__ unsigned short zl[2][16 * U];   // 8 KB  (lo)
    __shared__ float red[2][8];

    const int tid  = threadIdx.x;
    const int w    = tid >> 6;
    const int lane = tid & 63;
    const int l15  = lane & 15;
    const int lq   = lane >> 4;
    const int r0   = blockIdx.x * 16;
    const int c0   = w * 16;
    const int col  = c0 + l15;
    const int KD   = 784;

    // ---------------- Phase 1: input GEMM ----------------
    const float bv = bi[col];
    f32x4 a0 = {bv, bv, bv, bv};
    f32x4 a1 = {0.f, 0.f, 0.f, 0.f};
    f32x4 a2 = {0.f, 0.f, 0.f, 0.f};
    {
        const unsigned short* xhp = &Xh[(long)(r0 + l15) * KD];
        const unsigned short* xlp = &Xl[(long)(r0 + l15) * KD];
        const unsigned short* whp = &Wih[(long)col * KD];
        const unsigned short* wlp = &Wil[(long)col * KD];
        #pragma unroll 4
        for (int kc = 0; kc < 24; ++kc) {
            const int k = kc * 32 + lq * 8;
            bf16x8 ah = *(const bf16x8*)&xhp[k];
            bf16x8 al = *(const bf16x8*)&xlp[k];
            bf16x8 bh = *(const bf16x8*)&whp[k];
            bf16x8 bl = *(const bf16x8*)&wlp[k];
            a0 = MFMA(ah, bh, a0);
            a1 = MFMA(al, bh, a1);
            a2 = MFMA(ah, bl, a2);
        }
        // tail k = 768..783 (valid only lq<2)
        bf16x8 ah = {0,0,0,0,0,0,0,0}, al = ah, bh = ah, bl = ah;
        if (lq < 2) {
            const int k = 768 + lq * 8;
            ah = *(const bf16x8*)&xhp[k];
            al = *(const bf16x8*)&xlp[k];
            bh = *(const bf16x8*)&whp[k];
            bl = *(const bf16x8*)&wlp[k];
        }
        a0 = MFMA(ah, bh, a0);
        a1 = MFMA(al, bh, a1);
        a2 = MFMA(ah, bl, a2);
    }
    float xf[4], zr[4];
    #pragma unroll
    for (int i = 0; i < 4; ++i) xf[i] = a0[i] + a1[i] + a2[i];

    // ---------------- Phase 2: Picard layers ----------------
    // precomputed swizzled LDS byte offsets (loop-invariant)
    int offA[4];
    #pragma unroll
    for (int ks = 0; ks < 4; ++ks)
        offA[ks] = l15 * 256 + ((((ks * 32 + lq * 8) * 2)) ^ ((l15 & 7) << 4));
    int offW[4];
    #pragma unroll
    for (int i = 0; i < 4; ++i) {
        const int row = lq * 4 + i;
        offW[i] = row * 256 + ((col * 2) ^ ((row & 7) << 4));
    }
    char* zhB = (char*)&zh[0][0];
    char* zlB = (char*)&zl[0][0];

    int curFinal = 0;
    for (int l = 0; l < L; ++l) {
        // layer weights (pre-split bf16) -> registers for the whole loop
        bf16x8 whf[4], wlf[4];
        {
            const unsigned short* wbh = &Wbh[((long)l * U + col) * U];
            const unsigned short* wbl = &Wbl[((long)l * U + col) * U];
            #pragma unroll
            for (int ks = 0; ks < 4; ++ks) {
                const int k = ks * 32 + lq * 8;
                whf[ks] = *(const bf16x8*)&wbh[k];
                wlf[ks] = *(const bf16x8*)&wbl[k];
            }
        }

        // z0 = tanh(xf) -> LDS buf 0 (split at producer)
        #pragma unroll
        for (int i = 0; i < 4; ++i) {
            float t = tanh_fast(xf[i]);
            zr[i] = t;
            *(unsigned short*)(zhB + offW[i]) = hi16(t);
            *(unsigned short*)(zlB + offW[i]) = hi16(lo_of(t));
        }
        __syncthreads();

        int cur = 0;
        for (int it = 0; it < 50; ++it) {
            bf16x8 zhf[4], zlf[4];
            #pragma unroll
            for (int ks = 0; ks < 4; ++ks) {
                zhf[ks] = *(const bf16x8*)(zhB + cur * 4096 + offA[ks]);
                zlf[ks] = *(const bf16x8*)(zlB + cur * 4096 + offA[ks]);
            }
            f32x4 b0 = {xf[0], xf[1], xf[2], xf[3]};   // C-init = x
            f32x4 b1 = {0.f, 0.f, 0.f, 0.f};
            f32x4 b2 = {0.f, 0.f, 0.f, 0.f};
            #pragma unroll
            for (int ks = 0; ks < 4; ++ks) {
                b0 = MFMA(zhf[ks], whf[ks], b0);
                b1 = MFMA(zlf[ks], whf[ks], b1);
                b2 = MFMA(zhf[ks], wlf[ks], b2);
            }
            const int nxt = cur ^ 1;
            float dmax = 0.f;
            #pragma unroll
            for (int i = 0; i < 4; ++i) {
                float t = tanh_fast(b0[i] + b1[i] + b2[i]);
                dmax = fmaxf(dmax, fabsf(t - zr[i]));
                zr[i] = t;
                *(unsigned short*)(zhB + nxt * 4096 + offW[i]) = hi16(t);
                *(unsigned short*)(zlB + nxt * 4096 + offW[i]) = hi16(lo_of(t));
            }
            #pragma unroll
            for (int off = 32; off > 0; off >>= 1)
                dmax = fmaxf(dmax, __shfl_xor(dmax, off));
            if (lane == 0) red[it & 1][w] = dmax;
            __syncthreads();
            cur = nxt;
            float g = red[it & 1][0];
            #pragma unroll
            for (int q = 1; q < 8; ++q) g = fmaxf(g, red[it & 1][q]);
            if (g < 1e-5f) break;
        }
        curFinal = cur;
        #pragma unroll
        for (int i = 0; i < 4; ++i) xf[i] = zr[i];   // next layer's x = z*
    }

    // ---------------- Phase 3: output GEMM + softmax ----------------
    // wave w handles rows 2w, 2w+1. Final z reconstructed from LDS hi+lo.
    const char* zhF = zhB + curFinal * 4096;
    const char* zlF = zlB + curFinal * 4096;
    #pragma unroll
    for (int rr2 = 0; rr2 < 2; ++rr2) {
        const int rrow = 2 * w + rr2;
        const int o1 = rrow * 256 + ((lane * 2) ^ ((rrow & 7) << 4));
        const int o2 = rrow * 256 + (((lane + 64) * 2) ^ ((rrow & 7) << 4));
        const float zv0 = fromhi(*(const unsigned short*)(zhF + o1))
                        + fromhi(*(const unsigned short*)(zlF + o1));
        const float zv1 = fromhi(*(const unsigned short*)(zhF + o2))
                        + fromhi(*(const unsigned short*)(zlF + o2));
        float e[10];
        float m = -1e30f;
        #pragma unroll
        for (int o = 0; o < 10; ++o) {
            float p = zv0 * Wo[o * U + lane] + zv1 * Wo[o * U + 64 + lane];
            #pragma unroll
            for (int off = 32; off > 0; off >>= 1)
                p += __shfl_xor(p, off);
            p += bo[o];
            e[o] = p;
            m = fmaxf(m, p);
        }
        float s = 0.f;
        #pragma unroll
        for (int o = 0; o < 10; ++o) {
            e[o] = __expf(e[o] - m);
            s += e[o];
        }
        const float inv = 1.0f / s;
        float v = 0.f;
        #pragma unroll
        for (int o = 0; o < 10; ++o)
            if (lane == o) v = e[o] * inv;
        if (lane < 10) Out[(long)(r0 + rrow) * 10 + lane] = v;
    }
}

// ---------------------------------------------------------------------------
extern "C" void kernel_launch(void* const* d_in, const int* in_sizes, int n_in,
                              void* d_out, int out_size, void* d_ws, size_t ws_size,
                              hipStream_t stream) {
    const float* x  = (const float*)d_in[0];   // [B,784]
    const float* Wi = (const float*)d_in[1];   // [128,784]
    const float* bi = (const float*)d_in[2];   // [128]
    const float* Wb = (const float*)d_in[3];   // [L,128,128]
    const float* Wo = (const float*)d_in[4];   // [10,128]
    const float* bo = (const float*)d_in[5];   // [10]
    float* out = (float*)d_out;

    const int DIN = 784;
    const int B   = in_sizes[0] / DIN;             // 2048
    const int L   = in_sizes[3] / (U * U);         // 2

    const long nX  = (long)B * DIN;
    const long nWi = (long)U * DIN;
    const long nWb = (long)L * U * U;

    unsigned short* Xh  = (unsigned short*)d_ws;
    unsigned short* Xl  = Xh  + nX;
    unsigned short* Wih = Xl  + nX;
    unsigned short* Wil = Wih + nWi;
    unsigned short* WbhP= Wil + nWi;
    unsigned short* WblP= WbhP + nWb;

    const int n4X  = (int)(nX  / 4);
    const int n4Wi = (int)(nWi / 4);
    const int n4Wb = (int)(nWb / 4);
    const int tot4 = n4X + n4Wi + n4Wb;

    k_split<<<(tot4 + 255) / 256, 256, 0, stream>>>(
        x, Wi, Wb, Xh, Xl, Wih, Wil, WbhP, WblP, n4X, n4Wi, n4Wb);

    k_all<<<B / 16, 512, 0, stream>>>(
        Xh, Xl, Wih, Wil, WbhP, WblP, bi, Wo, bo, out, L);
}